// Round 1
// baseline (728.805 us; speedup 1.0000x reference)
//
#include <hip/hip_runtime.h>

#define B_ 32
#define T_ 2048
#define E_ 1024
#define H_ 1024
#define M_ (B_*T_)   // 65536 rows of enc

typedef __attribute__((ext_vector_type(8))) short short8;
typedef __attribute__((ext_vector_type(4))) float f32x4;

// ---- helpers -------------------------------------------------------------

__device__ __forceinline__ void gload_lds16(const void* g, void* l) {
  __builtin_amdgcn_global_load_lds(
      (const __attribute__((address_space(1))) void*)g,
      (__attribute__((address_space(3))) void*)l, 16, 0, 0);
}

// fp32 -> bf16, round-to-nearest-even (inputs are finite)
__device__ __forceinline__ short f2bf(float x) {
  unsigned u = __float_as_uint(x);
  unsigned r = (u + 0x7fffu + ((u >> 16) & 1u)) >> 16;
  return (short)r;
}

__device__ __forceinline__ float fast_tanh(float x) {
  float e = __expf(2.f * x);          // v_exp-based, ~1ulp
  return 1.f - 2.f / (e + 1.f);       // correct limits at +-inf
}

// ---- K0: W_enc [E][H] fp32  ->  Wt [H][E] bf16 (k-contiguous) ------------

__global__ __launch_bounds__(256) void k0_wt(const float* __restrict__ W,
                                             unsigned short* __restrict__ Wt) {
  __shared__ float t[32][33];
  int e0 = (blockIdx.x >> 5) << 5;
  int h0 = (blockIdx.x & 31) << 5;
  int r = threadIdx.x >> 5, c = threadIdx.x & 31;
#pragma unroll
  for (int i = 0; i < 4; ++i)
    t[r + i*8][c] = W[(size_t)(e0 + r + i*8) * H_ + h0 + c];
  __syncthreads();
#pragma unroll
  for (int i = 0; i < 4; ++i)
    Wt[(size_t)(h0 + r + i*8) * E_ + e0 + c] = (unsigned short)f2bf(t[c][r + i*8]);
}

// ---- K1: cvec[b][h] = b_enc[h] + b_dec[h] + sum_d dec[b][d]*W_dec[d][h] --

__global__ __launch_bounds__(256) void k1_cvec(const float* __restrict__ dec,
                                               const float* __restrict__ Wd,
                                               const float* __restrict__ b_enc,
                                               const float* __restrict__ b_dec,
                                               float* __restrict__ cvec) {
  __shared__ float ds[1024];
  int b = blockIdx.x >> 2, hb = blockIdx.x & 3;
  int tid = threadIdx.x;
#pragma unroll
  for (int i = 0; i < 4; ++i) ds[tid + i*256] = dec[b*1024 + tid + i*256];
  __syncthreads();
  int h = hb*256 + tid;
  float acc = b_enc[h] + b_dec[h];
#pragma unroll 8
  for (int d = 0; d < 1024; ++d) acc += ds[d] * Wd[(size_t)d * H_ + h];
  cvec[b*H_ + h] = acc;
}

// ---- K2: logits[m] += sum_n w_out[n]*tanh(enc[m,:]@W[:,n] + cvec[b][n]) --
// 128x128 tile, BK=32, 4 waves (2x2 of 64x64), mfma_f32_16x16x32_bf16.
// A staged fp32 via global_load_lds with XOR slot-swizzle (both sides);
// B staged bf16 linear. A converted to bf16 at fragment read.

__global__ __launch_bounds__(256) void k2_logits(
    const float* __restrict__ enc,              // [M_, E_] fp32
    const unsigned short* __restrict__ Wt,      // [H_, E_] bf16
    const float* __restrict__ cvec,             // [B_, H_]
    const float* __restrict__ w_out,            // [H_]
    float* __restrict__ logits)                 // [M_] (pre-zeroed, atomic)
{
  __shared__ float ldsA[128*32];            // 16 KB
  __shared__ unsigned short ldsB[128*32];   // 8 KB

  const int tid  = threadIdx.x;
  const int wave = tid >> 6, lane = tid & 63;
  const int lr = lane & 15, lk = lane >> 4;
  const int wr = wave >> 1, wc = wave & 1;
  const int bm = blockIdx.x >> 3, bn = blockIdx.x & 7;

  // staging descriptors (source pre-swizzled to match linear LDS dest)
  const float* asrc[4];
  void* adst[4];
#pragma unroll
  for (int i = 0; i < 4; ++i) {
    int pos  = i*4096 + wave*1024 + lane*16;  // byte pos in 16KB A tile
    int row  = pos >> 7;                      // 128B per row (32 fp32)
    int slot = (pos >> 4) & 7;                // 16B slot within row
    int ks   = (slot ^ (row & 7)) * 4;        // logical k-float offset
    asrc[i] = enc + (size_t)(bm*128 + row) * E_ + ks;
    adst[i] = (char*)ldsA + i*4096 + wave*1024;   // wave-uniform base
  }
  const unsigned short* bsrc[2];
  void* bdst[2];
#pragma unroll
  for (int i = 0; i < 2; ++i) {
    int pos  = i*4096 + wave*1024 + lane*16;  // byte pos in 8KB B tile
    int nrow = pos >> 6;                      // 64B per row (32 bf16)
    int ke   = (pos & 63) >> 1;               // bf16 element offset
    bsrc[i] = Wt + (size_t)(bn*128 + nrow) * E_ + ke;
    bdst[i] = (char*)ldsB + i*4096 + wave*1024;
  }

  f32x4 acc[4][4];
  {
    f32x4 z = {0.f, 0.f, 0.f, 0.f};
#pragma unroll
    for (int mi = 0; mi < 4; ++mi)
#pragma unroll
      for (int ni = 0; ni < 4; ++ni) acc[mi][ni] = z;
  }

  for (int kt = 0; kt < E_/32; ++kt) {
    if (kt) __syncthreads();
#pragma unroll
    for (int i = 0; i < 4; ++i) gload_lds16(asrc[i] + kt*32, adst[i]);
#pragma unroll
    for (int i = 0; i < 2; ++i) gload_lds16(bsrc[i] + kt*32, bdst[i]);
    __syncthreads();   // compiler drains vmcnt before s_barrier

    short8 bfr[4];
#pragma unroll
    for (int ni = 0; ni < 4; ++ni) {
      int nrow = wc*64 + ni*16 + lr;
      bfr[ni] = *(const short8*)((const char*)ldsB + nrow*64 + lk*16);
    }
    short8 afr[4];
#pragma unroll
    for (int mi = 0; mi < 4; ++mi) {
      int row = wr*64 + mi*16 + lr;
      int s1 = (2*lk)     ^ (row & 7);
      int s2 = (2*lk + 1) ^ (row & 7);
      f32x4 f1 = *(const f32x4*)((const char*)ldsA + row*128 + s1*16);
      f32x4 f2 = *(const f32x4*)((const char*)ldsA + row*128 + s2*16);
      short8 a;
      a[0] = f2bf(f1[0]); a[1] = f2bf(f1[1]); a[2] = f2bf(f1[2]); a[3] = f2bf(f1[3]);
      a[4] = f2bf(f2[0]); a[5] = f2bf(f2[1]); a[6] = f2bf(f2[2]); a[7] = f2bf(f2[3]);
      afr[mi] = a;
    }
#pragma unroll
    for (int mi = 0; mi < 4; ++mi)
#pragma unroll
      for (int ni = 0; ni < 4; ++ni)
        acc[mi][ni] = __builtin_amdgcn_mfma_f32_16x16x32_bf16(
            afr[mi], bfr[ni], acc[mi][ni], 0, 0, 0);
  }

  // epilogue: h = acc + cvec[n]; partial logit = sum_n w_out[n]*tanh(h)
  const int bIdx = bm >> 4;   // 2048/128 = 16 row-blocks per batch
  float cv[4], wv[4];
#pragma unroll
  for (int ni = 0; ni < 4; ++ni) {
    int n = bn*128 + wc*64 + ni*16 + lr;
    cv[ni] = cvec[bIdx*H_ + n];
    wv[ni] = w_out[n];
  }
#pragma unroll
  for (int mi = 0; mi < 4; ++mi) {
#pragma unroll
    for (int r = 0; r < 4; ++r) {
      float s = 0.f;
#pragma unroll
      for (int ni = 0; ni < 4; ++ni) {
        float h = acc[mi][ni][r] + cv[ni];
        s += wv[ni] * fast_tanh(h);
      }
      // reduce over the 16-lane group (covers this wave's 64 n-columns)
      s += __shfl_xor(s, 1);
      s += __shfl_xor(s, 2);
      s += __shfl_xor(s, 4);
      s += __shfl_xor(s, 8);
      if (lr == 0) {
        int m = bm*128 + wr*64 + mi*16 + lk*4 + r;
        atomicAdd(&logits[m], s);
      }
    }
  }
}

// ---- K3: masked softmax over T per batch; probs -> out ------------------

__global__ __launch_bounds__(256) void k3_softmax(
    const float* __restrict__ logits, const float* __restrict__ mask,
    const float* __restrict__ b_out, float* __restrict__ probs) {
  __shared__ float redm[4], reds[4];
  int b = blockIdx.x, tid = threadIdx.x;
  int wave = tid >> 6, lane = tid & 63;
  float bo = b_out[0];
  float lg[8];
  float mx = -1e30f;
#pragma unroll
  for (int i = 0; i < 8; ++i) {
    int t = i*256 + tid;
    float v = logits[b*T_ + t] + bo;
    v = (mask[b*T_ + t] > 0.f) ? v : -1e9f;
    lg[i] = v;
    mx = fmaxf(mx, v);
  }
#pragma unroll
  for (int off = 32; off; off >>= 1) mx = fmaxf(mx, __shfl_xor(mx, off));
  if (lane == 0) redm[wave] = mx;
  __syncthreads();
  mx = fmaxf(fmaxf(redm[0], redm[1]), fmaxf(redm[2], redm[3]));
  float sum = 0.f;
#pragma unroll
  for (int i = 0; i < 8; ++i) { lg[i] = __expf(lg[i] - mx); sum += lg[i]; }
#pragma unroll
  for (int off = 32; off; off >>= 1) sum += __shfl_xor(sum, off);
  if (lane == 0) reds[wave] = sum;
  __syncthreads();
  sum = reds[0] + reds[1] + reds[2] + reds[3];
  float inv = 1.f / sum;
#pragma unroll
  for (int i = 0; i < 8; ++i) {
    int t = i*256 + tid;
    probs[b*T_ + t] = lg[i] * inv;
  }
}

// ---- K4: attn[b][e] = sum_t probs[b][t] * enc[b][t][e] ------------------
// grid: 32 b * 64 t-splits; block covers all 1024 e (4 fp32/thread).

__global__ __launch_bounds__(256) void k4_attn(const float* __restrict__ enc,
                                               const float* __restrict__ probs,
                                               float* __restrict__ attn) {
  int bb = blockIdx.x >> 6;
  int t0 = (blockIdx.x & 63) * 32;
  int e0 = threadIdx.x * 4;
  float a0 = 0.f, a1 = 0.f, a2 = 0.f, a3 = 0.f;
#pragma unroll 4
  for (int tt = 0; tt < 32; ++tt) {
    int t = t0 + tt;
    float p = probs[bb*T_ + t];
    f32x4 v = *(const f32x4*)(enc + ((size_t)bb*T_ + t)*E_ + e0);
    a0 += p*v[0]; a1 += p*v[1]; a2 += p*v[2]; a3 += p*v[3];
  }
  atomicAdd(&attn[bb*E_ + e0 + 0], a0);
  atomicAdd(&attn[bb*E_ + e0 + 1], a1);
  atomicAdd(&attn[bb*E_ + e0 + 2], a2);
  atomicAdd(&attn[bb*E_ + e0 + 3], a3);
}

// ---- launch --------------------------------------------------------------

extern "C" void kernel_launch(void* const* d_in, const int* in_sizes, int n_in,
                              void* d_out, int out_size, void* d_ws, size_t ws_size,
                              hipStream_t stream) {
  const float* enc   = (const float*)d_in[0];
  const float* dec   = (const float*)d_in[1];
  const float* mask  = (const float*)d_in[2];
  const float* W_enc = (const float*)d_in[3];
  const float* b_enc = (const float*)d_in[4];
  const float* W_dec = (const float*)d_in[5];
  const float* b_dec = (const float*)d_in[6];
  const float* w_out = (const float*)d_in[7];
  const float* b_out = (const float*)d_in[8];

  float* out   = (float*)d_out;
  float* attn  = out;            // [32*1024]
  float* probs = out + B_*E_;    // [32*2048]

  char* ws = (char*)d_ws;
  unsigned short* Wt = (unsigned short*)ws;                 // 2 MB bf16 [H][E]
  float* cvec   = (float*)(ws + (2u<<20));                  // 128 KB
  float* logits = (float*)(ws + (2u<<20) + (128u<<10));     // 256 KB

  hipMemsetAsync(logits, 0, M_*sizeof(float), stream);
  hipMemsetAsync(attn,   0, B_*E_*sizeof(float), stream);

  k0_wt     <<<1024, 256, 0, stream>>>(W_enc, Wt);
  k1_cvec   <<< 128, 256, 0, stream>>>(dec, W_dec, b_enc, b_dec, cvec);
  k2_logits <<<4096, 256, 0, stream>>>(enc, Wt, cvec, w_out, logits);
  k3_softmax<<<  B_, 256, 0, stream>>>(logits, mask, b_out, probs);
  k4_attn   <<<2048, 256, 0, stream>>>(enc, probs, attn);
}

// Round 5
// 684.954 us; speedup vs baseline: 1.0640x; 1.0640x over previous
//
#include <hip/hip_runtime.h>

#define B_ 32
#define T_ 2048
#define E_ 1024
#define H_ 1024
#define M_ (B_*T_)   // 65536 rows of enc

typedef __attribute__((ext_vector_type(8))) short short8;
typedef __attribute__((ext_vector_type(4))) float f32x4;

// ---- helpers -------------------------------------------------------------

__device__ __forceinline__ void gload_lds16(const void* g, void* l) {
  __builtin_amdgcn_global_load_lds(
      (const __attribute__((address_space(1))) void*)g,
      (__attribute__((address_space(3))) void*)l, 16, 0, 0);
}

// fp32 -> bf16, round-to-nearest-even (inputs are finite)
__device__ __forceinline__ short f2bf(float x) {
  unsigned u = __float_as_uint(x);
  unsigned r = (u + 0x7fffu + ((u >> 16) & 1u)) >> 16;
  return (short)r;
}

__device__ __forceinline__ float fast_tanh(float x) {
  float e = __expf(2.f * x);
  return 1.f - 2.f / (e + 1.f);
}

// ---- K0: W_enc [E][H] fp32  ->  Wt [H][E] bf16 (k-contiguous) ------------

__global__ __launch_bounds__(256) void k0_wt(const float* __restrict__ W,
                                             unsigned short* __restrict__ Wt) {
  __shared__ float t[32][33];
  int e0 = (blockIdx.x >> 5) << 5;
  int h0 = (blockIdx.x & 31) << 5;
  int r = threadIdx.x >> 5, c = threadIdx.x & 31;
#pragma unroll
  for (int i = 0; i < 4; ++i)
    t[r + i*8][c] = W[(size_t)(e0 + r + i*8) * H_ + h0 + c];
  __syncthreads();
#pragma unroll
  for (int i = 0; i < 4; ++i)
    Wt[(size_t)(h0 + r + i*8) * E_ + e0 + c] = (unsigned short)f2bf(t[c][r + i*8]);
}

// ---- K0b: enc fp32 -> bf16, 16 elems/thread ------------------------------

__global__ __launch_bounds__(256) void k0b_cvt(const float* __restrict__ src,
                                               unsigned short* __restrict__ dst) {
  size_t base = ((size_t)blockIdx.x * 256 + threadIdx.x) * 16;
  const f32x4* s = (const f32x4*)(src + base);
  f32x4 a = s[0], b = s[1], c = s[2], d = s[3];
  short8 r0, r1;
  r0[0]=f2bf(a[0]); r0[1]=f2bf(a[1]); r0[2]=f2bf(a[2]); r0[3]=f2bf(a[3]);
  r0[4]=f2bf(b[0]); r0[5]=f2bf(b[1]); r0[6]=f2bf(b[2]); r0[7]=f2bf(b[3]);
  r1[0]=f2bf(c[0]); r1[1]=f2bf(c[1]); r1[2]=f2bf(c[2]); r1[3]=f2bf(c[3]);
  r1[4]=f2bf(d[0]); r1[5]=f2bf(d[1]); r1[6]=f2bf(d[2]); r1[7]=f2bf(d[3]);
  *(short8*)(dst + base)     = r0;
  *(short8*)(dst + base + 8) = r1;
}

// ---- K1: cvec[b][h] = b_enc[h] + b_dec[h] + sum_d dec[b][d]*W_dec[d][h] --

__global__ __launch_bounds__(256) void k1_cvec(const float* __restrict__ dec,
                                               const float* __restrict__ Wd,
                                               const float* __restrict__ b_enc,
                                               const float* __restrict__ b_dec,
                                               float* __restrict__ cvec) {
  __shared__ float ds[1024];
  int b = blockIdx.x >> 2, hb = blockIdx.x & 3;
  int tid = threadIdx.x;
#pragma unroll
  for (int i = 0; i < 4; ++i) ds[tid + i*256] = dec[b*1024 + tid + i*256];
  __syncthreads();
  int h = hb*256 + tid;
  float acc = b_enc[h] + b_dec[h];
#pragma unroll 8
  for (int d = 0; d < 1024; ++d) acc += ds[d] * Wd[(size_t)d * H_ + h];
  cvec[b*H_ + h] = acc;
}

// ---- K2: logits[m] += sum_n w_out[n]*tanh(enc[m,:]@W[:,n] + cvec[b][n]) --
// 128x128 tile, BK=64, 4 waves (2x2 of 64x64), mfma_f32_16x16x32_bf16.
// Both A and B staged bf16 with byte ^= ((row&7)<<4) XOR swizzle
// (pre-swizzled global source, linear gload_lds dest, swizzled ds_read).
// PRECVT: A from pre-converted bf16 enc via global_load_lds.
// !PRECVT: A reg-staged from fp32 enc with in-register cvt (ws fallback).

template<bool PRECVT>
__global__ __launch_bounds__(256) void k2_logits(
    const float* __restrict__ enc,              // [M_, E_] fp32
    const unsigned short* __restrict__ encbf,   // [M_, E_] bf16 (PRECVT)
    const unsigned short* __restrict__ Wt,      // [H_, E_] bf16
    const float* __restrict__ cvec,             // [B_, H_]
    const float* __restrict__ w_out,            // [H_]
    float* __restrict__ logits)                 // [M_] (pre-zeroed, atomic)
{
  __shared__ unsigned short ldsA[128*64];   // 16 KB
  __shared__ unsigned short ldsB[128*64];   // 16 KB

  const int tid  = threadIdx.x;
  const int wave = tid >> 6, lane = tid & 63;
  const int lr = lane & 15, lk = lane >> 4;
  const int wr = wave >> 1, wc = wave & 1;

  // XCD-bijective swizzle: nwg=4096, 8 XCDs -> each XCD gets 64 consecutive
  // bm row-tiles (all 8 bn each), so A rows stay L2-local per XCD.
  const int bid = blockIdx.x;
  const int swz = (bid & 7) * 512 + (bid >> 3);
  const int bm = swz >> 3, bn = swz & 7;

  // staging descriptors (source pre-swizzled to match linear LDS dest)
  const unsigned short* asrc[4];
  void* adst[4];
  const unsigned short* bsrc[4];
  void* bdst[4];
#pragma unroll
  for (int i = 0; i < 4; ++i) {
    int pos  = i*4096 + wave*1024 + lane*16;  // byte pos in 16KB tile
    int row  = pos >> 7;                      // 128 B per row (64 bf16)
    int slot = (pos >> 4) & 7;                // 16 B slot within row
    int klog = (slot ^ (row & 7)) * 8;        // logical bf16-k offset
    if (PRECVT)
      asrc[i] = encbf + (size_t)(bm*128 + row) * E_ + klog;
    bsrc[i] = Wt + (size_t)(bn*128 + row) * E_ + klog;
    adst[i] = (char*)ldsA + i*4096 + wave*1024;   // wave-uniform base
    bdst[i] = (char*)ldsB + i*4096 + wave*1024;
  }

  f32x4 acc[4][4];
  {
    f32x4 z = {0.f, 0.f, 0.f, 0.f};
#pragma unroll
    for (int mi = 0; mi < 4; ++mi)
#pragma unroll
      for (int ni = 0; ni < 4; ++ni) acc[mi][ni] = z;
  }

  for (int kt = 0; kt < E_/64; ++kt) {
    if (kt) __syncthreads();
#pragma unroll
    for (int i = 0; i < 4; ++i) gload_lds16(bsrc[i] + kt*64, bdst[i]);
    if constexpr (PRECVT) {
#pragma unroll
      for (int i = 0; i < 4; ++i) gload_lds16(asrc[i] + kt*64, adst[i]);
    } else {
#pragma unroll
      for (int c = 0; c < 4; ++c) {
        int chunk = tid + c*256;              // 0..1023 (16B chunks)
        int row = chunk >> 3, slot = chunk & 7;
        const float* g = enc + (size_t)(bm*128 + row) * E_ + kt*64 + slot*8;
        f32x4 f1 = *(const f32x4*)g;
        f32x4 f2 = *(const f32x4*)(g + 4);
        short8 a;
        a[0]=f2bf(f1[0]); a[1]=f2bf(f1[1]); a[2]=f2bf(f1[2]); a[3]=f2bf(f1[3]);
        a[4]=f2bf(f2[0]); a[5]=f2bf(f2[1]); a[6]=f2bf(f2[2]); a[7]=f2bf(f2[3]);
        *(short8*)((char*)ldsA + row*128 + ((slot ^ (row & 7)) << 4)) = a;
      }
    }
    __syncthreads();

#pragma unroll
    for (int ks = 0; ks < 2; ++ks) {
      short8 bfr[4], afr[4];
#pragma unroll
      for (int ni = 0; ni < 4; ++ni) {
        int nrow = wc*64 + ni*16 + lr;
        int ps = (ks*4 + lk) ^ (nrow & 7);
        bfr[ni] = *(const short8*)((const char*)ldsB + nrow*128 + ps*16);
      }
#pragma unroll
      for (int mi = 0; mi < 4; ++mi) {
        int row = wr*64 + mi*16 + lr;
        int ps = (ks*4 + lk) ^ (row & 7);
        afr[mi] = *(const short8*)((const char*)ldsA + row*128 + ps*16);
      }
#pragma unroll
      for (int mi = 0; mi < 4; ++mi)
#pragma unroll
        for (int ni = 0; ni < 4; ++ni)
          acc[mi][ni] = __builtin_amdgcn_mfma_f32_16x16x32_bf16(
              afr[mi], bfr[ni], acc[mi][ni], 0, 0, 0);
    }
  }

  // epilogue: h = acc + cvec[n]; partial logit = sum_n w_out[n]*tanh(h)
  const int bIdx = bm >> 4;   // 2048/128 = 16 row-blocks per batch
  float cv[4], wv[4];
#pragma unroll
  for (int ni = 0; ni < 4; ++ni) {
    int n = bn*128 + wc*64 + ni*16 + lr;
    cv[ni] = cvec[bIdx*H_ + n];
    wv[ni] = w_out[n];
  }
#pragma unroll
  for (int mi = 0; mi < 4; ++mi) {
#pragma unroll
    for (int r = 0; r < 4; ++r) {
      float s = 0.f;
#pragma unroll
      for (int ni = 0; ni < 4; ++ni) {
        float h = acc[mi][ni][r] + cv[ni];
        s += wv[ni] * fast_tanh(h);
      }
      s += __shfl_xor(s, 1);
      s += __shfl_xor(s, 2);
      s += __shfl_xor(s, 4);
      s += __shfl_xor(s, 8);
      if (lr == 0) {
        int m = bm*128 + wr*64 + mi*16 + lk*4 + r;
        atomicAdd(&logits[m], s);
      }
    }
  }
}

// ---- K3: masked softmax over T per batch; probs -> out ------------------

__global__ __launch_bounds__(256) void k3_softmax(
    const float* __restrict__ logits, const float* __restrict__ mask,
    const float* __restrict__ b_out, float* __restrict__ probs) {
  __shared__ float redm[4], reds[4];
  int b = blockIdx.x, tid = threadIdx.x;
  int wave = tid >> 6, lane = tid & 63;
  float bo = b_out[0];
  float lg[8];
  float mx = -1e30f;
#pragma unroll
  for (int i = 0; i < 8; ++i) {
    int t = i*256 + tid;
    float v = logits[b*T_ + t] + bo;
    v = (mask[b*T_ + t] > 0.f) ? v : -1e9f;
    lg[i] = v;
    mx = fmaxf(mx, v);
  }
#pragma unroll
  for (int off = 32; off; off >>= 1) mx = fmaxf(mx, __shfl_xor(mx, off));
  if (lane == 0) redm[wave] = mx;
  __syncthreads();
  mx = fmaxf(fmaxf(redm[0], redm[1]), fmaxf(redm[2], redm[3]));
  float sum = 0.f;
#pragma unroll
  for (int i = 0; i < 8; ++i) { lg[i] = __expf(lg[i] - mx); sum += lg[i]; }
#pragma unroll
  for (int off = 32; off; off >>= 1) sum += __shfl_xor(sum, off);
  if (lane == 0) reds[wave] = sum;
  __syncthreads();
  sum = reds[0] + reds[1] + reds[2] + reds[3];
  float inv = 1.f / sum;
#pragma unroll
  for (int i = 0; i < 8; ++i) {
    int t = i*256 + tid;
    probs[b*T_ + t] = lg[i] * inv;
  }
}

// ---- K4: attn[b][e] = sum_t probs[b][t] * enc[b][t][e] ------------------
// grid: 32 b * 16 t-splits (128 t per block); block covers all 1024 e.

__global__ __launch_bounds__(256) void k4_attn(const float* __restrict__ enc,
                                               const float* __restrict__ probs,
                                               float* __restrict__ attn) {
  int bb = blockIdx.x >> 4;
  int t0 = (blockIdx.x & 15) * 128;
  int e0 = threadIdx.x * 4;
  float a0 = 0.f, a1 = 0.f, a2 = 0.f, a3 = 0.f;
#pragma unroll 4
  for (int tt = 0; tt < 128; ++tt) {
    int t = t0 + tt;
    float p = probs[bb*T_ + t];
    f32x4 v = *(const f32x4*)(enc + ((size_t)bb*T_ + t)*E_ + e0);
    a0 += p*v[0]; a1 += p*v[1]; a2 += p*v[2]; a3 += p*v[3];
  }
  atomicAdd(&attn[bb*E_ + e0 + 0], a0);
  atomicAdd(&attn[bb*E_ + e0 + 1], a1);
  atomicAdd(&attn[bb*E_ + e0 + 2], a2);
  atomicAdd(&attn[bb*E_ + e0 + 3], a3);
}

// ---- launch --------------------------------------------------------------

extern "C" void kernel_launch(void* const* d_in, const int* in_sizes, int n_in,
                              void* d_out, int out_size, void* d_ws, size_t ws_size,
                              hipStream_t stream) {
  const float* enc   = (const float*)d_in[0];
  const float* dec   = (const float*)d_in[1];
  const float* mask  = (const float*)d_in[2];
  const float* W_enc = (const float*)d_in[3];
  const float* b_enc = (const float*)d_in[4];
  const float* W_dec = (const float*)d_in[5];
  const float* b_dec = (const float*)d_in[6];
  const float* w_out = (const float*)d_in[7];
  const float* b_out = (const float*)d_in[8];

  float* out   = (float*)d_out;
  float* attn  = out;            // [32*1024]
  float* probs = out + B_*E_;    // [32*2048]

  char* ws = (char*)d_ws;
  size_t off = 0;
  unsigned short* Wt = (unsigned short*)(ws + off);  off += (2u<<20);   // 2 MB
  float* cvec   = (float*)(ws + off);                off += (128u<<10);
  float* logits = (float*)(ws + off);                off += (256u<<10);
  unsigned short* encbf = (unsigned short*)(ws + off);
  const size_t need = off + (size_t)M_ * E_ * 2;     // +128 MB
  const bool precvt = (ws_size >= need);

  hipMemsetAsync(logits, 0, M_*sizeof(float), stream);
  hipMemsetAsync(attn,   0, B_*E_*sizeof(float), stream);

  k0_wt   <<<1024, 256, 0, stream>>>(W_enc, Wt);
  k1_cvec <<< 128, 256, 0, stream>>>(dec, W_dec, b_enc, b_dec, cvec);
  if (precvt) {
    k0b_cvt <<<16384, 256, 0, stream>>>(enc, encbf);
    k2_logits<true><<<4096, 256, 0, stream>>>(enc, encbf, Wt, cvec, w_out, logits);
  } else {
    k2_logits<false><<<4096, 256, 0, stream>>>(enc, encbf, Wt, cvec, w_out, logits);
  }
  k3_softmax<<<  B_, 256, 0, stream>>>(logits, mask, b_out, probs);
  k4_attn   <<< 512, 256, 0, stream>>>(enc, probs, attn);
}

// Round 7
// 594.077 us; speedup vs baseline: 1.2268x; 1.1530x over previous
//
#include <hip/hip_runtime.h>

#define B_ 32
#define T_ 2048
#define E_ 1024
#define H_ 1024
#define M_ (B_*T_)   // 65536 rows of enc

typedef __attribute__((ext_vector_type(8))) short short8;
typedef __attribute__((ext_vector_type(4))) float f32x4;

// ---- helpers -------------------------------------------------------------

__device__ __forceinline__ void gload_lds16(const void* g, void* l) {
  __builtin_amdgcn_global_load_lds(
      (const __attribute__((address_space(1))) void*)g,
      (__attribute__((address_space(3))) void*)l, 16, 0, 0);
}

// fp32 -> bf16, round-to-nearest-even (inputs are finite)
__device__ __forceinline__ short f2bf(float x) {
  unsigned u = __float_as_uint(x);
  unsigned r = (u + 0x7fffu + ((u >> 16) & 1u)) >> 16;
  return (short)r;
}

__device__ __forceinline__ float bf2f(unsigned short u) {
  return __uint_as_float(((unsigned)u) << 16);
}

__device__ __forceinline__ float fast_tanh(float x) {
  float e = __expf(2.f * x);
  return 1.f - 2.f / (e + 1.f);
}

// ---- prep: fused k0_wt (blocks 0..1023) + k1 d-split GEMV (1024..2047) ---
// k0: W_enc [E][H] fp32 -> Wt [H][E] bf16.
// k1: cvec[b][h] += sum_{d in chunk} dec[b][d]*W_dec[d][h]  (atomic, 8 chunks)
//     biases are folded into k2's epilogue; cvec pre-zeroed by memset.

__global__ __launch_bounds__(256) void prep(const float* __restrict__ W,
                                            unsigned short* __restrict__ Wt,
                                            const float* __restrict__ dec,
                                            const float* __restrict__ Wd,
                                            float* __restrict__ cvec) {
  __shared__ float smem[32*33];
  int bid = blockIdx.x;
  int tid = threadIdx.x;
  if (bid < 1024) {
    // ---- transpose W_enc -> Wt (bf16) ----
    int e0 = (bid >> 5) << 5;
    int h0 = (bid & 31) << 5;
    int r = tid >> 5, c = tid & 31;
#pragma unroll
    for (int i = 0; i < 4; ++i)
      smem[(r + i*8)*33 + c] = W[(size_t)(e0 + r + i*8) * H_ + h0 + c];
    __syncthreads();
#pragma unroll
    for (int i = 0; i < 4; ++i)
      Wt[(size_t)(h0 + r + i*8) * E_ + e0 + c] =
          (unsigned short)f2bf(smem[c*33 + r + i*8]);
  } else {
    // ---- dec @ W_dec partial (d-chunk of 128) ----
    int idx = bid - 1024;          // 0..1023 = 32 b x 4 hb x 8 ds
    int b  = idx >> 5;
    int hb = (idx >> 3) & 3;
    int ds = idx & 7;
    if (tid < 128) smem[tid] = dec[b*1024 + ds*128 + tid];
    __syncthreads();
    int h = hb*256 + tid;
    float acc = 0.f;
#pragma unroll 8
    for (int d = 0; d < 128; ++d)
      acc += smem[d] * Wd[(size_t)(ds*128 + d) * H_ + h];
    atomicAdd(&cvec[b*H_ + h], acc);
  }
}

// ---- K0b: enc fp32 -> bf16, 16 elems/thread ------------------------------

__global__ __launch_bounds__(256) void k0b_cvt(const float* __restrict__ src,
                                               unsigned short* __restrict__ dst) {
  size_t base = ((size_t)blockIdx.x * 256 + threadIdx.x) * 16;
  const f32x4* s = (const f32x4*)(src + base);
  f32x4 a = s[0], b = s[1], c = s[2], d = s[3];
  short8 r0, r1;
  r0[0]=f2bf(a[0]); r0[1]=f2bf(a[1]); r0[2]=f2bf(a[2]); r0[3]=f2bf(a[3]);
  r0[4]=f2bf(b[0]); r0[5]=f2bf(b[1]); r0[6]=f2bf(b[2]); r0[7]=f2bf(b[3]);
  r1[0]=f2bf(c[0]); r1[1]=f2bf(c[1]); r1[2]=f2bf(c[2]); r1[3]=f2bf(c[3]);
  r1[4]=f2bf(d[0]); r1[5]=f2bf(d[1]); r1[6]=f2bf(d[2]); r1[7]=f2bf(d[3]);
  *(short8*)(dst + base)     = r0;
  *(short8*)(dst + base + 8) = r1;
}

// ---- K2: logits[m] += sum_n w_out[n]*tanh(enc[m,:]@W[:,n] + cvec[b][n]) --
// 128x128 tile, BK=64, 4 waves (2x2 of 64x64), mfma_f32_16x16x32_bf16.
// Both A and B staged bf16 with byte ^= ((row&7)<<4) XOR swizzle
// (pre-swizzled global source, linear gload_lds dest, swizzled ds_read).
// PRECVT: A from pre-converted bf16 enc via global_load_lds.
// !PRECVT: A reg-staged from fp32 enc with in-register cvt (ws fallback).

template<bool PRECVT>
__global__ __launch_bounds__(256) void k2_logits(
    const float* __restrict__ enc,              // [M_, E_] fp32
    const unsigned short* __restrict__ encbf,   // [M_, E_] bf16 (PRECVT)
    const unsigned short* __restrict__ Wt,      // [H_, E_] bf16
    const float* __restrict__ cvec,             // [B_, H_] (dec@Wd partials)
    const float* __restrict__ b_enc,            // [H_]
    const float* __restrict__ b_dec,            // [H_]
    const float* __restrict__ w_out,            // [H_]
    float* __restrict__ logits)                 // [M_] (pre-zeroed, atomic)
{
  __shared__ unsigned short ldsA[128*64];   // 16 KB
  __shared__ unsigned short ldsB[128*64];   // 16 KB

  const int tid  = threadIdx.x;
  const int wave = tid >> 6, lane = tid & 63;
  const int lr = lane & 15, lk = lane >> 4;
  const int wr = wave >> 1, wc = wave & 1;

  // XCD-bijective swizzle: nwg=4096, 8 XCDs -> each XCD gets 64 consecutive
  // bm row-tiles (all 8 bn each), so A rows stay L2-local per XCD.
  const int bid = blockIdx.x;
  const int swz = (bid & 7) * 512 + (bid >> 3);
  const int bm = swz >> 3, bn = swz & 7;

  // staging descriptors (source pre-swizzled to match linear LDS dest)
  const unsigned short* asrc[4];
  void* adst[4];
  const unsigned short* bsrc[4];
  void* bdst[4];
#pragma unroll
  for (int i = 0; i < 4; ++i) {
    int pos  = i*4096 + wave*1024 + lane*16;  // byte pos in 16KB tile
    int row  = pos >> 7;                      // 128 B per row (64 bf16)
    int slot = (pos >> 4) & 7;                // 16 B slot within row
    int klog = (slot ^ (row & 7)) * 8;        // logical bf16-k offset
    if (PRECVT)
      asrc[i] = encbf + (size_t)(bm*128 + row) * E_ + klog;
    bsrc[i] = Wt + (size_t)(bn*128 + row) * E_ + klog;
    adst[i] = (char*)ldsA + i*4096 + wave*1024;   // wave-uniform base
    bdst[i] = (char*)ldsB + i*4096 + wave*1024;
  }

  f32x4 acc[4][4];
  {
    f32x4 z = {0.f, 0.f, 0.f, 0.f};
#pragma unroll
    for (int mi = 0; mi < 4; ++mi)
#pragma unroll
      for (int ni = 0; ni < 4; ++ni) acc[mi][ni] = z;
  }

  for (int kt = 0; kt < E_/64; ++kt) {
    if (kt) __syncthreads();
#pragma unroll
    for (int i = 0; i < 4; ++i) gload_lds16(bsrc[i] + kt*64, bdst[i]);
    if constexpr (PRECVT) {
#pragma unroll
      for (int i = 0; i < 4; ++i) gload_lds16(asrc[i] + kt*64, adst[i]);
    } else {
#pragma unroll
      for (int c = 0; c < 4; ++c) {
        int chunk = tid + c*256;              // 0..1023 (16B chunks)
        int row = chunk >> 3, slot = chunk & 7;
        const float* g = enc + (size_t)(bm*128 + row) * E_ + kt*64 + slot*8;
        f32x4 f1 = *(const f32x4*)g;
        f32x4 f2 = *(const f32x4*)(g + 4);
        short8 a;
        a[0]=f2bf(f1[0]); a[1]=f2bf(f1[1]); a[2]=f2bf(f1[2]); a[3]=f2bf(f1[3]);
        a[4]=f2bf(f2[0]); a[5]=f2bf(f2[1]); a[6]=f2bf(f2[2]); a[7]=f2bf(f2[3]);
        *(short8*)((char*)ldsA + row*128 + ((slot ^ (row & 7)) << 4)) = a;
      }
    }
    __syncthreads();

#pragma unroll
    for (int ks = 0; ks < 2; ++ks) {
      short8 bfr[4], afr[4];
#pragma unroll
      for (int ni = 0; ni < 4; ++ni) {
        int nrow = wc*64 + ni*16 + lr;
        int ps = (ks*4 + lk) ^ (nrow & 7);
        bfr[ni] = *(const short8*)((const char*)ldsB + nrow*128 + ps*16);
      }
#pragma unroll
      for (int mi = 0; mi < 4; ++mi) {
        int row = wr*64 + mi*16 + lr;
        int ps = (ks*4 + lk) ^ (row & 7);
        afr[mi] = *(const short8*)((const char*)ldsA + row*128 + ps*16);
      }
#pragma unroll
      for (int mi = 0; mi < 4; ++mi)
#pragma unroll
        for (int ni = 0; ni < 4; ++ni)
          acc[mi][ni] = __builtin_amdgcn_mfma_f32_16x16x32_bf16(
              afr[mi], bfr[ni], acc[mi][ni], 0, 0, 0);
    }
  }

  // epilogue: h = acc + cvec[n] + b_enc[n] + b_dec[n];
  // partial logit = sum_n w_out[n]*tanh(h)
  const int bIdx = bm >> 4;   // 2048/128 = 16 row-blocks per batch
  float cv[4], wv[4];
#pragma unroll
  for (int ni = 0; ni < 4; ++ni) {
    int n = bn*128 + wc*64 + ni*16 + lr;
    cv[ni] = cvec[bIdx*H_ + n] + b_enc[n] + b_dec[n];
    wv[ni] = w_out[n];
  }
#pragma unroll
  for (int mi = 0; mi < 4; ++mi) {
#pragma unroll
    for (int r = 0; r < 4; ++r) {
      float s = 0.f;
#pragma unroll
      for (int ni = 0; ni < 4; ++ni) {
        float h = acc[mi][ni][r] + cv[ni];
        s += wv[ni] * fast_tanh(h);
      }
      s += __shfl_xor(s, 1);
      s += __shfl_xor(s, 2);
      s += __shfl_xor(s, 4);
      s += __shfl_xor(s, 8);
      if (lr == 0) {
        int m = bm*128 + wr*64 + mi*16 + lk*4 + r;
        atomicAdd(&logits[m], s);
      }
    }
  }
}

// ---- K3: masked softmax over T per batch; probs -> out ------------------

__global__ __launch_bounds__(256) void k3_softmax(
    const float* __restrict__ logits, const float* __restrict__ mask,
    const float* __restrict__ b_out, float* __restrict__ probs) {
  __shared__ float redm[4], reds[4];
  int b = blockIdx.x, tid = threadIdx.x;
  int wave = tid >> 6, lane = tid & 63;
  float bo = b_out[0];
  float lg[8];
  float mx = -1e30f;
#pragma unroll
  for (int i = 0; i < 8; ++i) {
    int t = i*256 + tid;
    float v = logits[b*T_ + t] + bo;
    v = (mask[b*T_ + t] > 0.f) ? v : -1e9f;
    lg[i] = v;
    mx = fmaxf(mx, v);
  }
#pragma unroll
  for (int off = 32; off; off >>= 1) mx = fmaxf(mx, __shfl_xor(mx, off));
  if (lane == 0) redm[wave] = mx;
  __syncthreads();
  mx = fmaxf(fmaxf(redm[0], redm[1]), fmaxf(redm[2], redm[3]));
  float sum = 0.f;
#pragma unroll
  for (int i = 0; i < 8; ++i) { lg[i] = __expf(lg[i] - mx); sum += lg[i]; }
#pragma unroll
  for (int off = 32; off; off >>= 1) sum += __shfl_xor(sum, off);
  if (lane == 0) reds[wave] = sum;
  __syncthreads();
  sum = reds[0] + reds[1] + reds[2] + reds[3];
  float inv = 1.f / sum;
#pragma unroll
  for (int i = 0; i < 8; ++i) {
    int t = i*256 + tid;
    probs[b*T_ + t] = lg[i] * inv;
  }
}

// ---- K4: attn[b][e] = sum_t probs[b][t] * enc[b][t][e] ------------------
// grid: 32 b x 8 e-splits (128 e each); 256 threads = 16 t-groups x 16
// e-octs of 8. Vectorized short8 (bf16) or 2x f32x4 loads; LDS tg-reduce;
// direct store (no atomics, no memset).

template<bool USEBF>
__global__ __launch_bounds__(256) void k4_attn(
    const float* __restrict__ enc,
    const unsigned short* __restrict__ encbf,
    const float* __restrict__ probs,
    float* __restrict__ attn) {
  __shared__ float red[16][128];
  int b  = blockIdx.x >> 3;
  int es = blockIdx.x & 7;
  int tid = threadIdx.x;
  int eoct = tid & 15;        // 16 octs of 8 e-cols = 128
  int tg   = tid >> 4;        // 16 t-groups
  int ebase = es*128 + eoct*8;

  float a[8];
#pragma unroll
  for (int j = 0; j < 8; ++j) a[j] = 0.f;

#pragma unroll 4
  for (int t = tg; t < T_; t += 16) {
    float p = probs[b*T_ + t];
    size_t roff = ((size_t)b*T_ + t)*E_ + ebase;
    if constexpr (USEBF) {
      short8 v = *(const short8*)(encbf + roff);
#pragma unroll
      for (int j = 0; j < 8; ++j) a[j] += p * bf2f((unsigned short)v[j]);
    } else {
      f32x4 v1 = *(const f32x4*)(enc + roff);
      f32x4 v2 = *(const f32x4*)(enc + roff + 4);
#pragma unroll
      for (int j = 0; j < 4; ++j) { a[j] += p*v1[j]; a[4+j] += p*v2[j]; }
    }
  }
#pragma unroll
  for (int j = 0; j < 8; ++j) red[tg][eoct*8 + j] = a[j];
  __syncthreads();
  if (tid < 128) {
    float s = 0.f;
#pragma unroll
    for (int g = 0; g < 16; ++g) s += red[g][tid];
    attn[b*E_ + es*128 + tid] = s;
  }
}

// ---- launch --------------------------------------------------------------

extern "C" void kernel_launch(void* const* d_in, const int* in_sizes, int n_in,
                              void* d_out, int out_size, void* d_ws, size_t ws_size,
                              hipStream_t stream) {
  const float* enc   = (const float*)d_in[0];
  const float* dec   = (const float*)d_in[1];
  const float* mask  = (const float*)d_in[2];
  const float* W_enc = (const float*)d_in[3];
  const float* b_enc = (const float*)d_in[4];
  const float* W_dec = (const float*)d_in[5];
  const float* b_dec = (const float*)d_in[6];
  const float* w_out = (const float*)d_in[7];
  const float* b_out = (const float*)d_in[8];

  float* out   = (float*)d_out;
  float* attn  = out;            // [32*1024]
  float* probs = out + B_*E_;    // [32*2048]

  char* ws = (char*)d_ws;
  size_t off = 0;
  unsigned short* Wt = (unsigned short*)(ws + off);  off += (2u<<20);   // 2 MB
  float* cvec   = (float*)(ws + off);                off += (128u<<10); // 128 KB
  float* logits = (float*)(ws + off);                off += (256u<<10); // 256 KB
  unsigned short* encbf = (unsigned short*)(ws + off);
  const size_t need = off + (size_t)M_ * E_ * 2;     // +128 MB
  const bool precvt = (ws_size >= need);

  // one memset covers cvec + logits (adjacent in ws)
  hipMemsetAsync(cvec, 0, (128u<<10) + (256u<<10), stream);

  prep <<<2048, 256, 0, stream>>>(W_enc, Wt, dec, W_dec, cvec);
  if (precvt) {
    k0b_cvt <<<16384, 256, 0, stream>>>(enc, encbf);
    k2_logits<true><<<4096, 256, 0, stream>>>(enc, encbf, Wt, cvec,
                                              b_enc, b_dec, w_out, logits);
  } else {
    k2_logits<false><<<4096, 256, 0, stream>>>(enc, encbf, Wt, cvec,
                                               b_enc, b_dec, w_out, logits);
  }
  k3_softmax<<<B_, 256, 0, stream>>>(logits, mask, b_out, probs);
  if (precvt) {
    k4_attn<true> <<<256, 256, 0, stream>>>(enc, encbf, probs, attn);
  } else {
    k4_attn<false><<<256, 256, 0, stream>>>(enc, encbf, probs, attn);
  }
}